// Round 4
// baseline (416.232 us; speedup 1.0000x reference)
//
#include <hip/hip_runtime.h>

// Double bilinear grid_sample (align_corners=False, zeros padding), fused.
// feature: [8,64,256,256] f32 NCHW; grid: [8,256,256,2] f32.
//
// K1: transpose feature NCHW -> grouped NHWC16: [n][4][65536 px][16 ch].
//     256hw x 64c tiles, 1 KB contiguous nt reads, XOR-swizzled LDS,
//     16 KB contiguous nt write per (block, group) (fg is consumed on a
//     DIFFERENT XCD, so keeping it dirty in local L2 only adds an
//     end-of-kernel writeback stall).
// K2: fused double-sample, channel-split for L2 residency (r3: FETCH
//     797->232 MB, 245->170 us). r4: phase 2 lanes widened to float4 --
//     lane = (point, ch-quad), one dwordx4 per (point,entry) -> 16
//     points per wave instruction, 64 VMEM instr/block (r3: 256). Theory:
//     r3 was VMEM-issue/TA-bound (no pipe saturated: 27% HBM, ~37% L2,
//     57% VALU). Same 64 B segment count, 4x fewer instructions, ~2x
//     fewer VALU ops. Accumulation order per (point,channel) unchanged
//     -> bit-identical output.

#define GS_N 8
#define GS_C 64
#define GS_H 256
#define GS_W 256
#define GS_HW (GS_H * GS_W)
#define GS_IMG (GS_C * GS_HW)
#define GS_G 4                 // channel groups
#define GS_GC 16               // channels per group

typedef float f4v __attribute__((ext_vector_type(4)));

__global__ __launch_bounds__(256) void transpose_nchw_to_g16(
        const float* __restrict__ src, float* __restrict__ dst) {
    int b   = blockIdx.x;               // 2048 blocks: 256 hw x 64 c tile
    int n   = b >> 8;
    int hw0 = (b & 255) << 8;

    // Flat 64 KiB: row c = floats [c*256, c*256+256) as 64 float4 slots;
    // logical slot s of row c lives at phys slot s ^ (c>>3).
    __shared__ float lt[GS_C * 256];

    const float* sp = src + (size_t)n * GS_IMG + hw0;

    int l  = threadIdx.x & 63;
    int wv = threadIdx.x >> 6;

    // ---- Phase A: wave = one channel per instruction; 1 KB contiguous
    // nt read (feature is dead after this kernel).
    #pragma unroll
    for (int t = 0; t < 16; ++t) {
        int c = (wv << 4) + t;
        f4v v = __builtin_nontemporal_load(
                    (const f4v*)(sp + ((size_t)c << 16) + (l << 2)));
        int s = l ^ (c >> 3);           // swizzled float4 slot
        *(f4v*)&lt[(c << 8) + (s << 2)] = v;
    }
    __syncthreads();

    // ---- Phase B: write grouped NHWC16. c4 = float4 group of channels
    // [4*c4, 4*c4+4) = group g = c4>>2, in-row float offset (c4&3)*4.
    int c4  = threadIdx.x & 15;
    int h0  = threadIdx.x >> 4;
    int g   = c4 >> 2;
    int cl0 = (c4 & 3) << 2;
    int swz = c4 >> 1;                  // == (4*c4+k)>>3 for k=0..3
    int c0  = c4 << 2;
    float* dp = dst + ((size_t)(n * GS_G + g) << 20)   // 4 MB slice
              + ((size_t)hw0 << 4) + cl0;
    #pragma unroll
    for (int t = 0; t < 16; ++t) {
        int hh  = h0 + (t << 4);
        int col = (((hh >> 2) ^ swz) << 2) | (hh & 3);  // float idx in row
        f4v v;
        v.x = lt[((c0 + 0) << 8) + col];
        v.y = lt[((c0 + 1) << 8) + col];
        v.z = lt[((c0 + 2) << 8) + col];
        v.w = lt[((c0 + 3) << 8) + col];
        __builtin_nontemporal_store(v, (f4v*)(dp + ((size_t)hh << 4)));
    }
}

__device__ __forceinline__ void corner_setup(float gx, float gy,
        int& x0, int& y0, float& w00, float& w01, float& w10, float& w11) {
    // ix = ((gx+1)*256 - 1)*0.5 = gx*128 + 127.5
    float ix = fmaf(gx, 128.0f, 127.5f);
    float iy = fmaf(gy, 128.0f, 127.5f);
    float fx0 = floorf(ix), fy0 = floorf(iy);
    float fx = ix - fx0, fy = iy - fy0;
    x0 = (int)fx0; y0 = (int)fy0;
    int x1 = x0 + 1, y1 = y0 + 1;
    float mx0 = (x0 >= 0 && x0 < GS_W) ? 1.0f : 0.0f;
    float mx1 = (x1 >= 0 && x1 < GS_W) ? 1.0f : 0.0f;
    float my0 = (y0 >= 0 && y0 < GS_H) ? 1.0f : 0.0f;
    float my1 = (y1 >= 0 && y1 < GS_H) ? 1.0f : 0.0f;
    w00 = (1.0f - fx) * (1.0f - fy) * mx0 * my0;
    w01 = fx * (1.0f - fy) * mx1 * my0;
    w10 = (1.0f - fx) * fy * mx0 * my1;
    w11 = fx * fy * mx1 * my1;
}

__global__ __launch_bounds__(256) void gs_fused(
        const float* __restrict__ fg, const float* __restrict__ grid,
        float* __restrict__ out) {
    int bx  = blockIdx.x;              // 8192
    int g   = blockIdx.y;              // channel group (x-fastest dispatch)
    int n   = bx & 7;                  // XCD pin: (bx + 8192*g) % 8 == bx % 8
    int idx = bx >> 3;                 // 0..1023
    int p0  = (n << 16) + (idx << 6);  // first point (n,ho,wo0)

    __shared__ int2  s_desc[64][17];   // [point][entry] {byte_off, weight}
    __shared__ float tile[GS_GC][65];  // [ch-in-group][point]

    const float2* g2 = (const float2*)grid + (size_t)n * (size_t)GS_HW;

    // ---- Phase 1: all 256 threads; thread = (point, corner k).
    {
        int pt = threadIdx.x >> 2;
        int k  = threadIdx.x & 3;
        float2 gp = ((const float2*)grid)[p0 + pt];   // 4-thread broadcast
        int ox0, oy0; float w00, w01, w10, w11;
        corner_setup(gp.x, gp.y, ox0, oy0, w00, w01, w10, w11);
        int x0c = min(max(ox0, 0), GS_W - 1), x1c = min(max(ox0 + 1, 0), GS_W - 1);
        int y0c = min(max(oy0, 0), GS_H - 1), y1c = min(max(oy0 + 1, 0), GS_H - 1);
        int   qx = (k & 1) ? x1c : x0c;               // k order matches r3:
        int   qy = (k >> 1) ? y1c : y0c;              // 00,01,10,11
        float wk = (k == 0) ? w00 : (k == 1) ? w01 : (k == 2) ? w10 : w11;
        float2 gi = g2[qy * GS_W + qx];               // 8 B gather, L2-resident
        int ix0, iy0; float u00, u01, u10, u11;
        corner_setup(gi.x, gi.y, ix0, iy0, u00, u01, u10, u11);
        int a0 = min(max(ix0, 0), GS_W - 1), a1 = min(max(ix0 + 1, 0), GS_W - 1);
        int b0 = min(max(iy0, 0), GS_H - 1), b1 = min(max(iy0 + 1, 0), GS_H - 1);
        // byte offset of the 64 B group row: pixel * 16 ch * 4 B
        s_desc[pt][k * 4 + 0] = make_int2((b0 * GS_W + a0) << 6, __float_as_int(wk * u00));
        s_desc[pt][k * 4 + 1] = make_int2((b0 * GS_W + a1) << 6, __float_as_int(wk * u01));
        s_desc[pt][k * 4 + 2] = make_int2((b1 * GS_W + a0) << 6, __float_as_int(wk * u10));
        s_desc[pt][k * 4 + 3] = make_int2((b1 * GS_W + a1) << 6, __float_as_int(wk * u11));
    }
    __syncthreads();

    // ---- Phase 2: lane = (point pl, ch-quad q); 16 points per wave
    // instruction (dwordx4 per lane). 64 VMEM instr/block (r3: 256).
    {
        int lane = threadIdx.x & 63;
        int wave = threadIdx.x >> 6;
        int pl   = lane >> 2;          // 0..15: point within wave
        int q    = lane & 3;           // 0..3: channel quad
        int pt   = wave * 16 + pl;
        const char* fbc = (const char*)(fg + ((size_t)(n * GS_G + g) << 20))
                        + (q << 4);
        f4v acc = {0.0f, 0.0f, 0.0f, 0.0f};
        #pragma unroll
        for (int e = 0; e < 16; ++e) {
            int2 d = s_desc[pt][e];                   // 4-lane broadcast
            f4v v = *(const f4v*)(fbc + (size_t)d.x); // 64 B row / 4 lanes
            float w = __int_as_float(d.y);
            acc.x = fmaf(w, v.x, acc.x);
            acc.y = fmaf(w, v.y, acc.y);
            acc.z = fmaf(w, v.z, acc.z);
            acc.w = fmaf(w, v.w, acc.w);
        }
        int c0 = q << 2;
        tile[c0 + 0][pt] = acc.x;      // ~4-way LDS conflict, negligible
        tile[c0 + 1][pt] = acc.y;
        tile[c0 + 2][pt] = acc.z;
        tile[c0 + 3][pt] = acc.w;
    }
    __syncthreads();

    // ---- coalesced NCHW write, non-temporal (don't pollute L2 slice)
    int ho  = (p0 >> 8) & 255;
    int wo0 = p0 & 255;
    float* ob = out + (size_t)n * GS_IMG + ((size_t)(g * GS_GC) << 16)
              + (size_t)ho * GS_W + wo0;
    int w  = threadIdx.x & 63;
    int c0 = threadIdx.x >> 6;
    #pragma unroll
    for (int c = c0; c < GS_GC; c += 4)
        __builtin_nontemporal_store(tile[c][w], ob + ((size_t)c << 16) + w);
}

extern "C" void kernel_launch(void* const* d_in, const int* in_sizes, int n_in,
                              void* d_out, int out_size, void* d_ws, size_t ws_size,
                              hipStream_t stream) {
    const float* feature = (const float*)d_in[0];
    const float* grid    = (const float*)d_in[1];
    float*       out     = (float*)d_out;
    float*       fg      = (float*)d_ws;           // 128 MiB grouped-NHWC16

    dim3 block(256);

    transpose_nchw_to_g16<<<dim3(GS_N * GS_HW / 256), block, 0, stream>>>(feature, fg);
    gs_fused<<<dim3(GS_N * GS_HW / 64, GS_G), block, 0, stream>>>(fg, grid, out);
}

// Round 5
// 411.037 us; speedup vs baseline: 1.0126x; 1.0126x over previous
//
#include <hip/hip_runtime.h>

// Double bilinear grid_sample (align_corners=False, zeros padding), fused.
// feature: [8,64,256,256] f32 NCHW; grid: [8,256,256,2] f32.
//
// K1: transpose feature NCHW -> grouped NHWC16: [n][4][65536 px][16 ch].
//     256hw x 64c tiles, 1 KB contiguous nt reads, XOR-swizzled LDS,
//     16 KB contiguous nt writes (fg is consumed on a different XCD).
// K2: fused double-sample, channel-split for L2 residency (r3: FETCH
//     797->232 MB, 245->170 us). r4 (float4 lanes, 16 seg/instr) REGRESSED
//     to 209 us -> TA serializes segments within an instruction; keep r3's
//     4x64B-segment pattern. r5: cut issue overhead + raise MLP at fixed
//     segment count: desc rows padded to 144 B so TWO descriptors come in
//     per ds_read_b128 (halves LDS issue), 2 points unrolled per lane
//     (32 loads in flight, 2 indep acc chains), ch4 hoisted into base.
//     Per-(point,channel) fma order e=0..15 unchanged -> bit-identical.

#define GS_N 8
#define GS_C 64
#define GS_H 256
#define GS_W 256
#define GS_HW (GS_H * GS_W)
#define GS_IMG (GS_C * GS_HW)
#define GS_G 4                 // channel groups
#define GS_GC 16               // channels per group

typedef float f4v __attribute__((ext_vector_type(4)));

__global__ __launch_bounds__(256) void transpose_nchw_to_g16(
        const float* __restrict__ src, float* __restrict__ dst) {
    int b   = blockIdx.x;               // 2048 blocks: 256 hw x 64 c tile
    int n   = b >> 8;
    int hw0 = (b & 255) << 8;

    // Flat 64 KiB: row c = floats [c*256, c*256+256) as 64 float4 slots;
    // logical slot s of row c lives at phys slot s ^ (c>>3).
    __shared__ float lt[GS_C * 256];

    const float* sp = src + (size_t)n * GS_IMG + hw0;

    int l  = threadIdx.x & 63;
    int wv = threadIdx.x >> 6;

    // ---- Phase A: wave = one channel per instruction; 1 KB contiguous
    // nt read (feature is dead after this kernel).
    #pragma unroll
    for (int t = 0; t < 16; ++t) {
        int c = (wv << 4) + t;
        f4v v = __builtin_nontemporal_load(
                    (const f4v*)(sp + ((size_t)c << 16) + (l << 2)));
        int s = l ^ (c >> 3);           // swizzled float4 slot
        *(f4v*)&lt[(c << 8) + (s << 2)] = v;
    }
    __syncthreads();

    // ---- Phase B: write grouped NHWC16. c4 = float4 group of channels
    // [4*c4, 4*c4+4) = group g = c4>>2, in-row float offset (c4&3)*4.
    int c4  = threadIdx.x & 15;
    int h0  = threadIdx.x >> 4;
    int g   = c4 >> 2;
    int cl0 = (c4 & 3) << 2;
    int swz = c4 >> 1;                  // == (4*c4+k)>>3 for k=0..3
    int c0  = c4 << 2;
    float* dp = dst + ((size_t)(n * GS_G + g) << 20)   // 4 MB slice
              + ((size_t)hw0 << 4) + cl0;
    #pragma unroll
    for (int t = 0; t < 16; ++t) {
        int hh  = h0 + (t << 4);
        int col = (((hh >> 2) ^ swz) << 2) | (hh & 3);  // float idx in row
        f4v v;
        v.x = lt[((c0 + 0) << 8) + col];
        v.y = lt[((c0 + 1) << 8) + col];
        v.z = lt[((c0 + 2) << 8) + col];
        v.w = lt[((c0 + 3) << 8) + col];
        __builtin_nontemporal_store(v, (f4v*)(dp + ((size_t)hh << 4)));
    }
}

__device__ __forceinline__ void corner_setup(float gx, float gy,
        int& x0, int& y0, float& w00, float& w01, float& w10, float& w11) {
    // ix = ((gx+1)*256 - 1)*0.5 = gx*128 + 127.5
    float ix = fmaf(gx, 128.0f, 127.5f);
    float iy = fmaf(gy, 128.0f, 127.5f);
    float fx0 = floorf(ix), fy0 = floorf(iy);
    float fx = ix - fx0, fy = iy - fy0;
    x0 = (int)fx0; y0 = (int)fy0;
    int x1 = x0 + 1, y1 = y0 + 1;
    float mx0 = (x0 >= 0 && x0 < GS_W) ? 1.0f : 0.0f;
    float mx1 = (x1 >= 0 && x1 < GS_W) ? 1.0f : 0.0f;
    float my0 = (y0 >= 0 && y0 < GS_H) ? 1.0f : 0.0f;
    float my1 = (y1 >= 0 && y1 < GS_H) ? 1.0f : 0.0f;
    w00 = (1.0f - fx) * (1.0f - fy) * mx0 * my0;
    w01 = fx * (1.0f - fy) * mx1 * my0;
    w10 = (1.0f - fx) * fy * mx0 * my1;
    w11 = fx * fy * mx1 * my1;
}

__global__ __launch_bounds__(256) void gs_fused(
        const float* __restrict__ fg, const float* __restrict__ grid,
        float* __restrict__ out) {
    int bx  = blockIdx.x;              // 8192
    int g   = blockIdx.y;              // channel group (x-fastest dispatch)
    int n   = bx & 7;                  // XCD pin: (bx + 8192*g) % 8 == bx % 8
    int idx = bx >> 3;                 // 0..1023
    int p0  = (n << 16) + (idx << 6);  // first point (n,ho,wo0)

    // 18-entry rows: 144 B, 16 B-aligned -> ds_read_b128 reads desc pairs.
    __shared__ int2  s_desc[64][18];   // [point][entry] {byte_off, weight}
    __shared__ float tile[GS_GC][65];  // [ch-in-group][point]

    const float2* g2 = (const float2*)grid + (size_t)n * (size_t)GS_HW;

    // ---- Phase 1: all 256 threads; thread = (point, corner k).
    {
        int pt = threadIdx.x >> 2;
        int k  = threadIdx.x & 3;
        float2 gp = ((const float2*)grid)[p0 + pt];   // 4-thread broadcast
        int ox0, oy0; float w00, w01, w10, w11;
        corner_setup(gp.x, gp.y, ox0, oy0, w00, w01, w10, w11);
        int x0c = min(max(ox0, 0), GS_W - 1), x1c = min(max(ox0 + 1, 0), GS_W - 1);
        int y0c = min(max(oy0, 0), GS_H - 1), y1c = min(max(oy0 + 1, 0), GS_H - 1);
        int   qx = (k & 1) ? x1c : x0c;               // k order matches r3:
        int   qy = (k >> 1) ? y1c : y0c;              // 00,01,10,11
        float wk = (k == 0) ? w00 : (k == 1) ? w01 : (k == 2) ? w10 : w11;
        float2 gi = g2[qy * GS_W + qx];               // 8 B gather, L2-resident
        int ix0, iy0; float u00, u01, u10, u11;
        corner_setup(gi.x, gi.y, ix0, iy0, u00, u01, u10, u11);
        int a0 = min(max(ix0, 0), GS_W - 1), a1 = min(max(ix0 + 1, 0), GS_W - 1);
        int b0 = min(max(iy0, 0), GS_H - 1), b1 = min(max(iy0 + 1, 0), GS_H - 1);
        // byte offset of the 64 B group row: pixel * 16 ch * 4 B
        s_desc[pt][k * 4 + 0] = make_int2((b0 * GS_W + a0) << 6, __float_as_int(wk * u00));
        s_desc[pt][k * 4 + 1] = make_int2((b0 * GS_W + a1) << 6, __float_as_int(wk * u01));
        s_desc[pt][k * 4 + 2] = make_int2((b1 * GS_W + a0) << 6, __float_as_int(wk * u10));
        s_desc[pt][k * 4 + 3] = make_int2((b1 * GS_W + a1) << 6, __float_as_int(wk * u11));
    }
    __syncthreads();

    // ---- Phase 2: r3 mapping (lane = 4 pts x 16 ch -> 4x64B segments
    // per instr), but: desc pairs via ds_read_b128, 2 points unrolled
    // per lane (32 loads in flight), ch4 folded into the base pointer.
    {
        int lane = threadIdx.x & 63;
        int wave = threadIdx.x >> 6;
        int ch4  = (lane & 15) << 2;   // byte offset of channel in row
        int ps   = lane >> 4;          // 0..3: point within quartet
        const char* fbc = (const char*)(fg + ((size_t)(n * GS_G + g) << 20))
                        + ch4;
        #pragma unroll 1
        for (int s2 = 0; s2 < 2; ++s2) {
            int slA = wave * 16 + (s2 * 2 + 0) * 4 + ps;
            int slB = wave * 16 + (s2 * 2 + 1) * 4 + ps;
            float accA = 0.0f, accB = 0.0f;
            #pragma unroll
            for (int e = 0; e < 16; e += 2) {
                int4 dA = *(const int4*)&s_desc[slA][e];   // 2 descs, b128
                int4 dB = *(const int4*)&s_desc[slB][e];
                float vA0 = *(const float*)(fbc + (size_t)(unsigned)dA.x);
                float vA1 = *(const float*)(fbc + (size_t)(unsigned)dA.z);
                float vB0 = *(const float*)(fbc + (size_t)(unsigned)dB.x);
                float vB1 = *(const float*)(fbc + (size_t)(unsigned)dB.z);
                accA = fmaf(__int_as_float(dA.y), vA0, accA);
                accA = fmaf(__int_as_float(dA.w), vA1, accA);
                accB = fmaf(__int_as_float(dB.y), vB0, accB);
                accB = fmaf(__int_as_float(dB.w), vB1, accB);
            }
            tile[lane & 15][slA] = accA;
            tile[lane & 15][slB] = accB;
        }
    }
    __syncthreads();

    // ---- coalesced NCHW write, non-temporal (don't pollute L2 slice)
    int ho  = (p0 >> 8) & 255;
    int wo0 = p0 & 255;
    float* ob = out + (size_t)n * GS_IMG + ((size_t)(g * GS_GC) << 16)
              + (size_t)ho * GS_W + wo0;
    int w  = threadIdx.x & 63;
    int c0 = threadIdx.x >> 6;
    #pragma unroll
    for (int c = c0; c < GS_GC; c += 4)
        __builtin_nontemporal_store(tile[c][w], ob + ((size_t)c << 16) + w);
}

extern "C" void kernel_launch(void* const* d_in, const int* in_sizes, int n_in,
                              void* d_out, int out_size, void* d_ws, size_t ws_size,
                              hipStream_t stream) {
    const float* feature = (const float*)d_in[0];
    const float* grid    = (const float*)d_in[1];
    float*       out     = (float*)d_out;
    float*       fg      = (float*)d_ws;           // 128 MiB grouped-NHWC16

    dim3 block(256);

    transpose_nchw_to_g16<<<dim3(GS_N * GS_HW / 256), block, 0, stream>>>(feature, fg);
    gs_fused<<<dim3(GS_N * GS_HW / 64, GS_G), block, 0, stream>>>(fg, grid, out);
}